// Round 1
// baseline (17721.126 us; speedup 1.0000x reference)
//
#include <hip/hip_runtime.h>
#include <hip/hip_bf16.h>
#include <cstdint>
#include <cstddef>

#define DD 128

static constexpr int NU = 100000;
static constexpr int NI = 100000;
static constexpr int NB = 100000;
static constexpr int NNODE = 200000;   // U+I == B+I
static constexpr int NBATCH = 4096;

// ---------------- kernels ----------------

__global__ void hist_kernel(const int* __restrict__ src, int ne, unsigned* __restrict__ deg) {
    int i = blockIdx.x * blockDim.x + threadIdx.x;
    if (i < ne) atomicAdd(&deg[src[i]], 1u);
}

__global__ void deg_to_dinv(float* __restrict__ buf, int n) {
    int i = blockIdx.x * blockDim.x + threadIdx.x;
    if (i < n) {
        unsigned c = reinterpret_cast<const unsigned*>(buf)[i];
        buf[i] = (c > 0u) ? rsqrtf((float)c) : 0.0f;
    }
}

// acc = xa = concat(p0, p1); operates in float4 units
__global__ void init_concat(const float* __restrict__ p0, const float* __restrict__ p1,
                            size_t f0, size_t ftot,
                            float* __restrict__ acc, float* __restrict__ xa) {
    size_t i = (size_t)blockIdx.x * blockDim.x + threadIdx.x;
    if (i >= ftot) return;
    float4 v = (i < f0) ? reinterpret_cast<const float4*>(p0)[i]
                        : reinterpret_cast<const float4*>(p1)[i - f0];
    reinterpret_cast<float4*>(acc)[i] = v;
    reinterpret_cast<float4*>(xa)[i]  = v;
}

// one edge per 64 lanes (one wave), float2 per lane: coalesced 512B gather,
// 128 HW f32 atomics scatter-add
__global__ void scatter_kernel(const int* __restrict__ esrc, const int* __restrict__ edst,
                               int ne, const float* __restrict__ dinv,
                               const float* __restrict__ xin, float* __restrict__ xout) {
    size_t tid = (size_t)blockIdx.x * blockDim.x + threadIdx.x;
    int e = (int)(tid >> 6);
    if (e >= ne) return;
    int lane = (int)(tid & 63);
    int s = esrc[e];
    int d = edst[e];
    float w = dinv[s] * dinv[d];
    const float2 xv = *reinterpret_cast<const float2*>(xin + (size_t)d * DD + lane * 2);
    float* o = xout + (size_t)s * DD + lane * 2;
    unsafeAtomicAdd(o,     w * xv.x);
    unsafeAtomicAdd(o + 1, w * xv.y);
}

// acc = (acc + xk) * scale   (float4 units)
__global__ void acc_scale(float* __restrict__ acc, const float* __restrict__ xk,
                          size_t n4, float scale) {
    size_t i = (size_t)blockIdx.x * blockDim.x + threadIdx.x;
    if (i >= n4) return;
    float4 a = reinterpret_cast<const float4*>(acc)[i];
    float4 x = reinterpret_cast<const float4*>(xk)[i];
    a.x = (a.x + x.x) * scale;
    a.y = (a.y + x.y) * scale;
    a.z = (a.z + x.z) * scale;
    a.w = (a.w + x.w) * scale;
    reinterpret_cast<float4*>(acc)[i] = a;
}

// out[r] = base[idx[r] + off]   rows of 128 floats; 32 lanes x float4 per row
__global__ void gather_rows(const float* __restrict__ base, const int* __restrict__ idx,
                            int off, int nrows, float* __restrict__ out) {
    int tid = blockIdx.x * blockDim.x + threadIdx.x;
    int r = tid >> 5;
    if (r >= nrows) return;
    int lane = tid & 31;
    size_t srow = (size_t)(idx[r] + off);
    float4 v = *reinterpret_cast<const float4*>(base + srow * DD + lane * 4);
    *reinterpret_cast<float4*>(out + (size_t)r * DD + lane * 4) = v;
}

// ---------------- host-side helper ----------------

static void run_lightgcn(const int* edges, int ne,
                         const float* p0, int n0, const float* p1, int n1,
                         int K, float* acc, float* xA, float* xB, float* dinvbuf,
                         hipStream_t stream) {
    int n = n0 + n1;
    // degree histogram -> dinv (in place)
    hipMemsetAsync(dinvbuf, 0, (size_t)n * sizeof(float), stream);
    hist_kernel<<<(ne + 255) / 256, 256, 0, stream>>>(edges, ne, (unsigned*)dinvbuf);
    deg_to_dinv<<<(n + 255) / 256, 256, 0, stream>>>(dinvbuf, n);

    size_t ftot = (size_t)n * DD / 4;   // float4 count
    size_t f0   = (size_t)n0 * DD / 4;
    init_concat<<<(int)((ftot + 255) / 256), 256, 0, stream>>>(p0, p1, f0, ftot, acc, xA);

    const int* esrc = edges;
    const int* edst = edges + ne;
    float fin = 1.0f / (float)(K + 1);
    for (int k = 0; k < K; ++k) {
        hipMemsetAsync(xB, 0, (size_t)n * DD * sizeof(float), stream);
        size_t tthreads = (size_t)ne * 64;
        scatter_kernel<<<(int)((tthreads + 255) / 256), 256, 0, stream>>>(
            esrc, edst, ne, dinvbuf, xA, xB);
        acc_scale<<<(int)((ftot + 255) / 256), 256, 0, stream>>>(
            acc, xB, ftot, (k == K - 1) ? fin : 1.0f);
        float* t = xA; xA = xB; xB = t;
    }
}

// ---------------- entry ----------------

extern "C" void kernel_launch(void* const* d_in, const int* in_sizes, int n_in,
                              void* d_out, int out_size, void* d_ws, size_t ws_size,
                              hipStream_t stream) {
    const float* users_emb   = (const float*)d_in[0];
    const float* items_emb   = (const float*)d_in[1];
    const float* baskets_emb = (const float*)d_in[2];
    const int* baskets   = (const int*)d_in[3];
    const int* pos_items = (const int*)d_in[4];
    const int* neg_items = (const int*)d_in[5];
    const int* users     = (const int*)d_in[6];
    const int* u2i       = (const int*)d_in[7];
    const int* b2i       = (const int*)d_in[8];
    const int* u2i_aug   = (const int*)d_in[9];
    const int* b2i_aug   = (const int*)d_in[10];

    int ne_u  = in_sizes[7] / 2;   // 2E
    int ne_b  = in_sizes[8] / 2;
    int ne_ua = in_sizes[9] / 2;
    int ne_ba = in_sizes[10] / 2;

    float* out = (float*)d_out;
    float* ws  = (float*)d_ws;

    // workspace layout (floats): [dinv: 1M] [xA: 25.6M] [xB: 25.6M]  ~209 MB
    float* dinvbuf = ws;
    float* xA = ws + (1 << 20);
    float* xB = xA + (size_t)NNODE * DD;

    // output row segments
    float* ef1 = out;                                   // users1 | items1
    float* ef2 = out + 1 * (size_t)NNODE * DD;          // users2 | items2
    float* bf1 = out + 2 * (size_t)NNODE * DD;          // baskets1 | bitems1
    float* bf2 = out + 3 * (size_t)NNODE * DD;          // baskets2 | bitems2
    float* gout = out + 4 * (size_t)NNODE * DD;         // 6 x BATCH x D gathers

    run_lightgcn(u2i,     ne_u,  users_emb,   NU, items_emb, NI, 2, ef1, xA, xB, dinvbuf, stream);
    run_lightgcn(u2i_aug, ne_ua, users_emb,   NU, items_emb, NI, 2, ef2, xA, xB, dinvbuf, stream);
    run_lightgcn(b2i,     ne_b,  baskets_emb, NB, items_emb, NI, 3, bf1, xA, xB, dinvbuf, stream);
    run_lightgcn(b2i_aug, ne_ba, baskets_emb, NB, items_emb, NI, 3, bf2, xA, xB, dinvbuf, stream);

    // gathers: pos_e, neg_e (items1 = ef1 rows U+idx); pos_e1, neg_e1 (bitems1 = bf1 rows B+idx);
    // batch_user (users_emb rows users); batch_basket (bf1 rows baskets)
    int gt = NBATCH * 32;
    int gb = (gt + 255) / 256;
    gather_rows<<<gb, 256, 0, stream>>>(ef1, pos_items, NU, NBATCH, gout + 0 * (size_t)NBATCH * DD);
    gather_rows<<<gb, 256, 0, stream>>>(ef1, neg_items, NU, NBATCH, gout + 1 * (size_t)NBATCH * DD);
    gather_rows<<<gb, 256, 0, stream>>>(bf1, pos_items, NB, NBATCH, gout + 2 * (size_t)NBATCH * DD);
    gather_rows<<<gb, 256, 0, stream>>>(bf1, neg_items, NB, NBATCH, gout + 3 * (size_t)NBATCH * DD);
    gather_rows<<<gb, 256, 0, stream>>>(users_emb, users, 0, NBATCH, gout + 4 * (size_t)NBATCH * DD);
    gather_rows<<<gb, 256, 0, stream>>>(bf1, baskets, 0, NBATCH, gout + 5 * (size_t)NBATCH * DD);
}